// Round 1
// baseline (761.499 us; speedup 1.0000x reference)
//
#include <hip/hip_runtime.h>

// TemporalAttention: algebraically folded implementation.
//   score[h,n] = (M[h] q_in) . kv[n],  M[h] = W_K[h]^T W_Q[h]   (444x272)
//   out       = sum_h P[h] vt[h] + b_O, P[h] = W_O[:,h] W_V[h]  (272x444)
//   vt[h]     = sum_n softmax(score)[h,n] * kv[n]
// kv = [nbr_node(172) | nbr_edge(172) | nbr_time(100)]  (444)
// q  = [node(172) | time(100)]                          (272)

namespace {
constexpr int kB = 16384;
constexpr int kN = 20;
constexpr float kScale = 0.08574929257125441f;  // 1/sqrt(136)
constexpr float kLnEps = 1e-5f;

// ws float offsets
constexpr size_t kOffM4 = 0;                          // [68][888][4]
constexpr size_t kOffP4 = kOffM4 + 68ull * 888 * 4;   // [222][272][4]
constexpr size_t kOffWOT = kOffP4 + 222ull * 272 * 4; // [272][272]
constexpr size_t kOffQT = kOffWOT + 272ull * 272;     // [B][888] (q~ then v~ in-place)
}  // namespace

__device__ __forceinline__ float fma4(float4 a, float4 b, float acc) {
  acc = fmaf(a.x, b.x, acc);
  acc = fmaf(a.y, b.y, acc);
  acc = fmaf(a.z, b.z, acc);
  acc = fmaf(a.w, b.w, acc);
  return acc;
}

__global__ __launch_bounds__(256) void k_transpose_wo(const float* __restrict__ WO,
                                                      float* __restrict__ WOT) {
  int idx = blockIdx.x * 256 + threadIdx.x;
  if (idx >= 272 * 272) return;
  int i = idx / 272, o = idx % 272;
  WOT[idx] = WO[o * 272 + i];  // WOT[i][o]
}

// M4[i4][jj][c] = sum_d WQ[h*136+d][i4*4+c] * WK[h*136+d][j],  jj = h*444+j
__global__ __launch_bounds__(256) void k_build_m4(const float* __restrict__ WQ,
                                                  const float* __restrict__ WK,
                                                  float* __restrict__ M4) {
  int idx = blockIdx.x * 256 + threadIdx.x;
  if (idx >= 68 * 888) return;
  int i4 = idx / 888, jj = idx % 888;
  int h = jj / 444, j = jj - h * 444;
  float a0 = 0.f, a1 = 0.f, a2 = 0.f, a3 = 0.f;
  for (int d = 0; d < 136; ++d) {
    const float4 wq = *reinterpret_cast<const float4*>(WQ + (h * 136 + d) * 272 + i4 * 4);
    const float wk = WK[(h * 136 + d) * 444 + j];
    a0 = fmaf(wq.x, wk, a0);
    a1 = fmaf(wq.y, wk, a1);
    a2 = fmaf(wq.z, wk, a2);
    a3 = fmaf(wq.w, wk, a3);
  }
  float4 r;
  r.x = a0; r.y = a1; r.z = a2; r.w = a3;
  reinterpret_cast<float4*>(M4)[idx] = r;
}

// P4[j4][o][c] = sum_d WO[o][h*136+d] * WV[h*136+d][4*j4 - h*444 + c]
__global__ __launch_bounds__(256) void k_build_p4(const float* __restrict__ WOT,
                                                  const float* __restrict__ WV,
                                                  float* __restrict__ P4) {
  int idx = blockIdx.x * 256 + threadIdx.x;
  if (idx >= 222 * 272) return;
  int j4 = idx / 272, o = idx % 272;
  int h = (j4 < 111) ? 0 : 1;
  int jb = 4 * j4 - h * 444;
  float a0 = 0.f, a1 = 0.f, a2 = 0.f, a3 = 0.f;
  for (int d = 0; d < 136; ++d) {
    const float wo = WOT[(h * 136 + d) * 272 + o];  // coalesced over o
    const float4 wv = *reinterpret_cast<const float4*>(WV + (h * 136 + d) * 444 + jb);
    a0 = fmaf(wo, wv.x, a0);
    a1 = fmaf(wo, wv.y, a1);
    a2 = fmaf(wo, wv.z, a2);
    a3 = fmaf(wo, wv.w, a3);
  }
  float4 r;
  r.x = a0; r.y = a1; r.z = a2; r.w = a3;
  reinterpret_cast<float4*>(P4)[idx] = r;
}

// Phase A: QT[b][jj] = sum_i M[jj][i] q[b][i]; 16 rows per wg, thread owns jj=4t..4t+3
__global__ __launch_bounds__(256) void k_qtilde(const float* __restrict__ node,
                                                const float* __restrict__ timef,
                                                const float* __restrict__ M4,
                                                float* __restrict__ QT) {
  const int t = threadIdx.x;
  const int b0 = blockIdx.x * 16;
  if (t >= 222) return;
  float acc0[16], acc1[16], acc2[16], acc3[16];
#pragma unroll
  for (int bb = 0; bb < 16; ++bb) { acc0[bb] = 0.f; acc1[bb] = 0.f; acc2[bb] = 0.f; acc3[bb] = 0.f; }
  const float4* M4v = reinterpret_cast<const float4*>(M4);
  const float4* node4 = reinterpret_cast<const float4*>(node);  // rows of 43 float4
  const float4* time4 = reinterpret_cast<const float4*>(timef); // rows of 25 float4
  for (int i4 = 0; i4 < 68; ++i4) {
    const float4 m0 = M4v[(size_t)i4 * 888 + 4 * t + 0];
    const float4 m1 = M4v[(size_t)i4 * 888 + 4 * t + 1];
    const float4 m2 = M4v[(size_t)i4 * 888 + 4 * t + 2];
    const float4 m3 = M4v[(size_t)i4 * 888 + 4 * t + 3];
#pragma unroll
    for (int bb = 0; bb < 16; ++bb) {
      const int b = b0 + bb;
      const float4 q = (i4 < 43) ? node4[(size_t)b * 43 + i4]
                                 : time4[(size_t)b * 25 + (i4 - 43)];
      acc0[bb] = fma4(m0, q, acc0[bb]);
      acc1[bb] = fma4(m1, q, acc1[bb]);
      acc2[bb] = fma4(m2, q, acc2[bb]);
      acc3[bb] = fma4(m3, q, acc3[bb]);
    }
  }
  float4* QT4 = reinterpret_cast<float4*>(QT);
#pragma unroll
  for (int bb = 0; bb < 16; ++bb) {
    float4 r;
    r.x = acc0[bb]; r.y = acc1[bb]; r.z = acc2[bb]; r.w = acc3[bb];
    QT4[(size_t)(b0 + bb) * 222 + t] = r;
  }
}

// Phase B: one wave per batch row. Online softmax, kv read exactly once.
// Lane l holds float4 slots j4 = l (s0) and 64+l if l<47 (s1); 111 slots = 444 floats.
__global__ __launch_bounds__(256) void k_attn(const float* __restrict__ nnode,
                                              const float* __restrict__ nedge,
                                              const float* __restrict__ ntime,
                                              const int* __restrict__ mask,
                                              float* __restrict__ QT) {
  const int l = threadIdx.x & 63;
  const int w = threadIdx.x >> 6;
  const int b = blockIdx.x * 4 + w;
  const bool v1 = (l < 47);
  float4* QT4 = reinterpret_cast<float4*>(QT);
  const float4* nnode4 = reinterpret_cast<const float4*>(nnode);  // rows of 43
  const float4* nedge4 = reinterpret_cast<const float4*>(nedge);  // rows of 43
  const float4* ntime4 = reinterpret_cast<const float4*>(ntime);  // rows of 25
  const float4 z4 = make_float4(0.f, 0.f, 0.f, 0.f);

  const size_t qb = (size_t)b * 222;
  const float4 q00 = QT4[qb + l];
  const float4 q01 = v1 ? QT4[qb + 64 + l] : z4;
  const float4 q10 = QT4[qb + 111 + l];
  const float4 q11 = v1 ? QT4[qb + 111 + 64 + l] : z4;

  float4 va00 = z4, va01 = z4, va10 = z4, va11 = z4;
  float m0 = -1e30f, m1 = -1e30f, l0 = 0.f, l1 = 0.f;

  for (int n = 0; n < kN; ++n) {
    const size_t row = (size_t)b * kN + n;
    // slot 0: j4 = l in [0,64): node (<43) else edge
    float4 kv0 = (l < 43) ? nnode4[row * 43 + l] : nedge4[row * 43 + (l - 43)];
    // slot 1: j4 = 64+l in [64,111): edge (<86) else time
    float4 kv1 = z4;
    if (v1) {
      const int j4 = 64 + l;
      kv1 = (j4 < 86) ? nedge4[row * 43 + (j4 - 43)] : ntime4[row * 25 + (j4 - 86)];
    }
    float ps0 = fma4(q01, kv1, fma4(q00, kv0, 0.f));
    float ps1 = fma4(q11, kv1, fma4(q10, kv0, 0.f));
#pragma unroll
    for (int off = 32; off >= 1; off >>= 1) {
      ps0 += __shfl_xor(ps0, off, 64);
      ps1 += __shfl_xor(ps1, off, 64);
    }
    const int mk = mask[row];
    const float s0 = (mk == 0) ? -1e10f : ps0 * kScale;
    const float s1 = (mk == 0) ? -1e10f : ps1 * kScale;

    // head 0
    {
      const float mn = fmaxf(m0, s0);
      const float al = __expf(m0 - mn);
      const float p = __expf(s0 - mn);
      l0 = l0 * al + p;
      m0 = mn;
      va00.x = fmaf(p, kv0.x, va00.x * al);
      va00.y = fmaf(p, kv0.y, va00.y * al);
      va00.z = fmaf(p, kv0.z, va00.z * al);
      va00.w = fmaf(p, kv0.w, va00.w * al);
      va01.x = fmaf(p, kv1.x, va01.x * al);
      va01.y = fmaf(p, kv1.y, va01.y * al);
      va01.z = fmaf(p, kv1.z, va01.z * al);
      va01.w = fmaf(p, kv1.w, va01.w * al);
    }
    // head 1
    {
      const float mn = fmaxf(m1, s1);
      const float al = __expf(m1 - mn);
      const float p = __expf(s1 - mn);
      l1 = l1 * al + p;
      m1 = mn;
      va10.x = fmaf(p, kv0.x, va10.x * al);
      va10.y = fmaf(p, kv0.y, va10.y * al);
      va10.z = fmaf(p, kv0.z, va10.z * al);
      va10.w = fmaf(p, kv0.w, va10.w * al);
      va11.x = fmaf(p, kv1.x, va11.x * al);
      va11.y = fmaf(p, kv1.y, va11.y * al);
      va11.z = fmaf(p, kv1.z, va11.z * al);
      va11.w = fmaf(p, kv1.w, va11.w * al);
    }
  }
  const float i0 = 1.0f / l0;
  const float i1 = 1.0f / l1;
  va00.x *= i0; va00.y *= i0; va00.z *= i0; va00.w *= i0;
  va01.x *= i0; va01.y *= i0; va01.z *= i0; va01.w *= i0;
  va10.x *= i1; va10.y *= i1; va10.z *= i1; va10.w *= i1;
  va11.x *= i1; va11.y *= i1; va11.z *= i1; va11.w *= i1;
  // overwrite q~ with v~ (all reads of q~ completed above)
  QT4[qb + l] = va00;
  if (v1) QT4[qb + 64 + l] = va01;
  QT4[qb + 111 + l] = va10;
  if (v1) QT4[qb + 111 + 64 + l] = va11;
}

// Phase C: out[b][o] = bO[o] + sum_j P[o][j] vt[b][j]; + residual + LayerNorm
__global__ __launch_bounds__(256) void k_out(const float* __restrict__ VT,
                                             const float* __restrict__ P4,
                                             const float* __restrict__ node,
                                             const float* __restrict__ timef,
                                             const float* __restrict__ bO,
                                             const float* __restrict__ g,
                                             const float* __restrict__ be,
                                             float* __restrict__ out) {
  __shared__ float xl[16][272];
  const int t = threadIdx.x;
  const int b0 = blockIdx.x * 16;
  const bool ex = (t < 16);  // these threads also own o = 256+t
  float acc[16], acc2[16];
#pragma unroll
  for (int bb = 0; bb < 16; ++bb) { acc[bb] = 0.f; acc2[bb] = 0.f; }
  const float4* P4v = reinterpret_cast<const float4*>(P4);
  const float4* VT4 = reinterpret_cast<const float4*>(VT);
  const float4 z4 = make_float4(0.f, 0.f, 0.f, 0.f);
  for (int j4 = 0; j4 < 222; ++j4) {
    const float4 p0 = P4v[(size_t)j4 * 272 + t];
    const float4 p1 = ex ? P4v[(size_t)j4 * 272 + 256 + t] : z4;
#pragma unroll
    for (int bb = 0; bb < 16; ++bb) {
      const float4 vs = VT4[(size_t)(b0 + bb) * 222 + j4];  // wave-uniform
      acc[bb] = fma4(p0, vs, acc[bb]);
      if (ex) acc2[bb] = fma4(p1, vs, acc2[bb]);
    }
  }
  // bias + residual into LDS
#pragma unroll
  for (int bb = 0; bb < 16; ++bb) {
    const int b = b0 + bb;
    const float q = (t < 172) ? node[(size_t)b * 172 + t] : timef[(size_t)b * 100 + (t - 172)];
    xl[bb][t] = acc[bb] + bO[t] + q;
    if (ex) {
      const int o2 = 256 + t;
      const float q2 = timef[(size_t)b * 100 + (o2 - 172)];
      xl[bb][o2] = acc2[bb] + bO[o2] + q2;
    }
  }
  __syncthreads();
  // LayerNorm: wave w handles rows bb = w, w+4, w+8, w+12
  const int w = t >> 6, l = t & 63;
  for (int bb = w; bb < 16; bb += 4) {
    float sum = 0.f, sq = 0.f;
#pragma unroll
    for (int k = 0; k < 5; ++k) {
      const int o = l + 64 * k;
      if (o < 272) {
        const float v = xl[bb][o];
        sum += v;
        sq = fmaf(v, v, sq);
      }
    }
#pragma unroll
    for (int off = 32; off >= 1; off >>= 1) {
      sum += __shfl_xor(sum, off, 64);
      sq += __shfl_xor(sq, off, 64);
    }
    const float mu = sum * (1.0f / 272.0f);
    const float var = sq * (1.0f / 272.0f) - mu * mu;
    const float rs = rsqrtf(var + kLnEps);
#pragma unroll
    for (int k = 0; k < 5; ++k) {
      const int o = l + 64 * k;
      if (o < 272) {
        const float v = (xl[bb][o] - mu) * rs * g[o] + be[o];
        out[(size_t)(b0 + bb) * 272 + o] = v;
      }
    }
  }
}

extern "C" void kernel_launch(void* const* d_in, const int* in_sizes, int n_in,
                              void* d_out, int out_size, void* d_ws, size_t ws_size,
                              hipStream_t stream) {
  const float* node = (const float*)d_in[0];
  const float* timef = (const float*)d_in[1];
  const float* nnode = (const float*)d_in[2];
  const float* ntime = (const float*)d_in[3];
  const float* nedge = (const float*)d_in[4];
  const int* mask = (const int*)d_in[5];
  const float* WQ = (const float*)d_in[6];
  const float* WK = (const float*)d_in[7];
  const float* WV = (const float*)d_in[8];
  const float* WO = (const float*)d_in[9];
  const float* bO = (const float*)d_in[10];
  const float* g = (const float*)d_in[11];
  const float* be = (const float*)d_in[12];

  float* ws = (float*)d_ws;
  float* M4 = ws + kOffM4;
  float* P4 = ws + kOffP4;
  float* WOT = ws + kOffWOT;
  float* QT = ws + kOffQT;
  float* out = (float*)d_out;

  hipLaunchKernelGGL(k_transpose_wo, dim3((272 * 272 + 255) / 256), dim3(256), 0, stream, WO, WOT);
  hipLaunchKernelGGL(k_build_m4, dim3((68 * 888 + 255) / 256), dim3(256), 0, stream, WQ, WK, M4);
  hipLaunchKernelGGL(k_build_p4, dim3((222 * 272 + 255) / 256), dim3(256), 0, stream, WOT, WV, P4);
  hipLaunchKernelGGL(k_qtilde, dim3(kB / 16), dim3(256), 0, stream, node, timef, M4, QT);
  hipLaunchKernelGGL(k_attn, dim3(kB / 4), dim3(256), 0, stream, nnode, nedge, ntime, mask, QT);
  hipLaunchKernelGGL(k_out, dim3(kB / 16), dim3(256), 0, stream, QT, P4, node, timef, bO, g, be, out);
}

// Round 2
// 333.805 us; speedup vs baseline: 2.2813x; 2.2813x over previous
//
#include <hip/hip_runtime.h>

// TemporalAttention, algebraically folded + MFMA for the two matvec phases.
//   A-phase: QT[B,896] = A16[B,288(pad)] @ Mmat[288,896]   (bf16 MFMA)
//   B-phase: online-softmax attention over kv (fp32, streaming)
//   C-phase: X[B,272] = VT[B,896] @ Pmat[896,272] + bias + residual + LN
// Column layout jj' = h*448 + j (j<444 valid, 444..447 pad, per head h).

namespace {
constexpr int kB = 16384;
constexpr int kN = 20;
constexpr float kScale = 0.08574929257125441f;  // 1/sqrt(136)
constexpr float kLnEps = 1e-5f;

// ws byte offsets
constexpr size_t kOffWOT = 0;                         // float[272*272]
constexpr size_t kOffMsw = 295936;                    // ushort[56*9*64*8]
constexpr size_t kOffPsw = kOffMsw + 516096;          // ushort[17*28*64*8]
constexpr size_t kOffA16 = kOffPsw + 487424;          // ushort[16384*288]
constexpr size_t kOffQT16 = kOffA16 + 9437184;        // ushort[16384*896]
}  // namespace

typedef __attribute__((ext_vector_type(8))) short s8v;
typedef __attribute__((ext_vector_type(4))) float f4v;

__device__ __forceinline__ unsigned short f2bf(float x) {
  unsigned int u = __float_as_uint(x);
  unsigned int r = (u + 0x7FFFu + ((u >> 16) & 1u)) >> 16;
  return (unsigned short)r;
}
__device__ __forceinline__ float bf2f(unsigned short h) {
  return __uint_as_float(((unsigned int)h) << 16);
}
__device__ __forceinline__ float fma4(float4 a, float4 b, float acc) {
  acc = fmaf(a.x, b.x, acc);
  acc = fmaf(a.y, b.y, acc);
  acc = fmaf(a.z, b.z, acc);
  acc = fmaf(a.w, b.w, acc);
  return acc;
}

__global__ __launch_bounds__(256) void k_transpose_wo(const float* __restrict__ WO,
                                                      float* __restrict__ WOT) {
  int idx = blockIdx.x * 256 + threadIdx.x;
  if (idx >= 272 * 272) return;
  int i = idx / 272, o = idx % 272;
  WOT[idx] = WO[o * 272 + i];  // WOT[i][o]
}

// Msw[tile 0..55][ks 0..8][lane][e 0..7]: B-frag order for GEMM-A.
// element = Mmat[i = ks*32+(l>>4)*8+e][jj = tile*16+(l&15)],
// Mmat[i][h*448+j] = sum_d WQ[h*136+d][i] * WK[h*136+d][j]; 0 if pad.
__global__ __launch_bounds__(64) void k_build_msw(const float* __restrict__ WQ,
                                                  const float* __restrict__ WK,
                                                  unsigned short* __restrict__ Msw) {
  const int tile = blockIdx.x / 9;
  const int ks = blockIdx.x % 9;
  const int l = threadIdx.x;
  const int jj = tile * 16 + (l & 15);
  const int h = jj / 448;
  const int j = jj - h * 448;
  const int i0 = ks * 32 + (l >> 4) * 8;
  const bool jvalid = (j < 444);
  unsigned short* dst = Msw + ((size_t)(tile * 9 + ks) * 64 + l) * 8;
#pragma unroll
  for (int e = 0; e < 8; ++e) {
    const int i = i0 + e;
    float s = 0.f;
    if (jvalid && i < 272) {
      const float* wq = WQ + h * 136 * 272 + i;
      const float* wk = WK + h * 136 * 444 + j;
#pragma unroll 4
      for (int d = 0; d < 136; ++d) s = fmaf(wq[d * 272], wk[d * 444], s);
    }
    dst[e] = f2bf(s);
  }
}

// Psw[tile 0..16][ks 0..27][lane][e]: B-frag order for GEMM-C.
// element = Pmat[k = ks*32+(l>>4)*8+e][n = tile*16+(l&15)],
// Pmat[h*448+j][n] = sum_d WO[n][h*136+d] * WV[h*136+d][j]; 0 if pad.
__global__ __launch_bounds__(64) void k_build_psw(const float* __restrict__ WOT,
                                                  const float* __restrict__ WV,
                                                  unsigned short* __restrict__ Psw) {
  const int tile = blockIdx.x / 28;
  const int ks = blockIdx.x % 28;
  const int l = threadIdx.x;
  const int n = tile * 16 + (l & 15);
  const int k0 = ks * 32 + (l >> 4) * 8;
  unsigned short* dst = Psw + ((size_t)(tile * 28 + ks) * 64 + l) * 8;
#pragma unroll
  for (int e = 0; e < 8; ++e) {
    const int k = k0 + e;
    const int h = k / 448;
    const int j = k - h * 448;
    float s = 0.f;
    if (j < 444) {
      const float* wo = WOT + h * 136 * 272 + n;
      const float* wv = WV + h * 136 * 444 + j;
#pragma unroll 4
      for (int d = 0; d < 136; ++d) s = fmaf(wo[d * 272], wv[d * 444], s);
    }
    dst[e] = f2bf(s);
  }
}

// A16[b][0..287] = bf16(cat(node,time)), zero pad.
__global__ __launch_bounds__(256) void k_cast_q(const float* __restrict__ node,
                                                const float* __restrict__ timef,
                                                unsigned short* __restrict__ A16) {
  const int idx = blockIdx.x * 256 + threadIdx.x;  // grid sized exactly
  const int b = idx / 288, i = idx - b * 288;
  float v = 0.f;
  if (i < 172) v = node[(size_t)b * 172 + i];
  else if (i < 272) v = timef[(size_t)b * 100 + (i - 172)];
  A16[idx] = f2bf(v);
}

// GEMM-A: QT16[16 rows/block][896] = A16 @ Mmat. 4 waves x 14 n-tiles.
__global__ __launch_bounds__(256) void k_gemm_a(const unsigned short* __restrict__ A16,
                                                const unsigned short* __restrict__ Msw,
                                                unsigned short* __restrict__ QT16) {
  const int tid = threadIdx.x;
  const int l = tid & 63, w = tid >> 6;
  const int m0 = blockIdx.x * 16;
  const int mrow = m0 + (l & 15);
  const int koff = (l >> 4) * 8;
  f4v acc[14];
#pragma unroll
  for (int t = 0; t < 14; ++t) acc[t] = (f4v){0.f, 0.f, 0.f, 0.f};
  for (int ks = 0; ks < 9; ++ks) {
    const s8v a = *reinterpret_cast<const s8v*>(A16 + (size_t)mrow * 288 + ks * 32 + koff);
    const unsigned short* bp = Msw + ((size_t)(w * 14) * 9 + ks) * 64 * 8 + (size_t)l * 8;
#pragma unroll
    for (int t = 0; t < 14; ++t) {
      const s8v b = *reinterpret_cast<const s8v*>(bp + (size_t)t * 9 * 64 * 8);
      acc[t] = __builtin_amdgcn_mfma_f32_16x16x32_bf16(a, b, acc[t], 0, 0, 0);
    }
  }
  const int r0 = (l >> 4) * 4;
#pragma unroll
  for (int t = 0; t < 14; ++t) {
    const int n = (w * 14 + t) * 16 + (l & 15);
#pragma unroll
    for (int r = 0; r < 4; ++r)
      QT16[(size_t)(m0 + r0 + r) * 896 + n] = f2bf(acc[t][r]);
  }
}

// Phase B: one wave per batch row; online softmax; kv read once.
// QT16 row: [h0 j=0..443 |pad| h1 at 448 j=0..443 |pad], bf16.
__global__ __launch_bounds__(256) void k_attn(const float* __restrict__ nnode,
                                              const float* __restrict__ nedge,
                                              const float* __restrict__ ntime,
                                              const int* __restrict__ mask,
                                              unsigned short* __restrict__ QT16) {
  const int l = threadIdx.x & 63;
  const int w = threadIdx.x >> 6;
  const int b = blockIdx.x * 4 + w;
  const bool v1 = (l < 47);
  const float4* nnode4 = reinterpret_cast<const float4*>(nnode);  // rows of 43
  const float4* nedge4 = reinterpret_cast<const float4*>(nedge);  // rows of 43
  const float4* ntime4 = reinterpret_cast<const float4*>(ntime);  // rows of 25
  const float4 z4 = make_float4(0.f, 0.f, 0.f, 0.f);
  unsigned short* qrow = QT16 + (size_t)b * 896;

  auto ldq = [&](int so) {
    const ushort4 u = *reinterpret_cast<const ushort4*>(qrow + so);
    return make_float4(bf2f(u.x), bf2f(u.y), bf2f(u.z), bf2f(u.w));
  };
  const float4 q00 = ldq(4 * l);
  const float4 q01 = v1 ? ldq(256 + 4 * l) : z4;
  const float4 q10 = ldq(448 + 4 * l);
  const float4 q11 = v1 ? ldq(448 + 256 + 4 * l) : z4;

  float4 va00 = z4, va01 = z4, va10 = z4, va11 = z4;
  float m0 = -1e30f, m1 = -1e30f, l0 = 0.f, l1 = 0.f;

  for (int n = 0; n < kN; ++n) {
    const size_t row = (size_t)b * kN + n;
    float4 kv0 = (l < 43) ? nnode4[row * 43 + l] : nedge4[row * 43 + (l - 43)];
    float4 kv1 = z4;
    if (v1) {
      const int j4 = 64 + l;
      kv1 = (j4 < 86) ? nedge4[row * 43 + (j4 - 43)] : ntime4[row * 25 + (j4 - 86)];
    }
    float ps0 = fma4(q01, kv1, fma4(q00, kv0, 0.f));
    float ps1 = fma4(q11, kv1, fma4(q10, kv0, 0.f));
#pragma unroll
    for (int off = 32; off >= 1; off >>= 1) {
      ps0 += __shfl_xor(ps0, off, 64);
      ps1 += __shfl_xor(ps1, off, 64);
    }
    const int mk = mask[row];
    const float s0 = (mk == 0) ? -1e10f : ps0 * kScale;
    const float s1 = (mk == 0) ? -1e10f : ps1 * kScale;
    {
      const float mn = fmaxf(m0, s0);
      const float al = __expf(m0 - mn);
      const float p = __expf(s0 - mn);
      l0 = l0 * al + p;
      m0 = mn;
      va00.x = fmaf(p, kv0.x, va00.x * al);
      va00.y = fmaf(p, kv0.y, va00.y * al);
      va00.z = fmaf(p, kv0.z, va00.z * al);
      va00.w = fmaf(p, kv0.w, va00.w * al);
      va01.x = fmaf(p, kv1.x, va01.x * al);
      va01.y = fmaf(p, kv1.y, va01.y * al);
      va01.z = fmaf(p, kv1.z, va01.z * al);
      va01.w = fmaf(p, kv1.w, va01.w * al);
    }
    {
      const float mn = fmaxf(m1, s1);
      const float al = __expf(m1 - mn);
      const float p = __expf(s1 - mn);
      l1 = l1 * al + p;
      m1 = mn;
      va10.x = fmaf(p, kv0.x, va10.x * al);
      va10.y = fmaf(p, kv0.y, va10.y * al);
      va10.z = fmaf(p, kv0.z, va10.z * al);
      va10.w = fmaf(p, kv0.w, va10.w * al);
      va11.x = fmaf(p, kv1.x, va11.x * al);
      va11.y = fmaf(p, kv1.y, va11.y * al);
      va11.z = fmaf(p, kv1.z, va11.z * al);
      va11.w = fmaf(p, kv1.w, va11.w * al);
    }
  }
  const float i0 = 1.0f / l0;
  const float i1 = 1.0f / l1;
  auto stq = [&](int so, float4 v, float s) {
    ushort4 u;
    u.x = f2bf(v.x * s); u.y = f2bf(v.y * s); u.z = f2bf(v.z * s); u.w = f2bf(v.w * s);
    *reinterpret_cast<ushort4*>(qrow + so) = u;
  };
  stq(4 * l, va00, i0);
  if (v1) stq(256 + 4 * l, va01, i0);
  stq(448 + 4 * l, va10, i1);
  if (v1) stq(448 + 256 + 4 * l, va11, i1);
}

// GEMM-C + bias + residual + LayerNorm. 4 waves; wave w owns n-tiles w,w+4,...
__global__ __launch_bounds__(256) void k_out_mfma(const unsigned short* __restrict__ VT16,
                                                  const unsigned short* __restrict__ Psw,
                                                  const float* __restrict__ node,
                                                  const float* __restrict__ timef,
                                                  const float* __restrict__ bO,
                                                  const float* __restrict__ g,
                                                  const float* __restrict__ be,
                                                  float* __restrict__ out) {
  __shared__ float xl[16][273];
  const int tid = threadIdx.x;
  const int l = tid & 63, w = tid >> 6;
  const int m0 = blockIdx.x * 16;
  const int mrow = m0 + (l & 15);
  const int koff = (l >> 4) * 8;
  f4v acc[5];
#pragma unroll
  for (int i = 0; i < 5; ++i) acc[i] = (f4v){0.f, 0.f, 0.f, 0.f};
  for (int ks = 0; ks < 28; ++ks) {
    const s8v a = *reinterpret_cast<const s8v*>(VT16 + (size_t)mrow * 896 + ks * 32 + koff);
#pragma unroll
    for (int i = 0; i < 5; ++i) {
      const int t = w + 4 * i;
      if (t < 17) {
        const s8v bfr = *reinterpret_cast<const s8v*>(Psw + ((size_t)(t * 28 + ks) * 64 + l) * 8);
        acc[i] = __builtin_amdgcn_mfma_f32_16x16x32_bf16(a, bfr, acc[i], 0, 0, 0);
      }
    }
  }
  const int r0 = (l >> 4) * 4;
#pragma unroll
  for (int i = 0; i < 5; ++i) {
    const int t = w + 4 * i;
    if (t < 17) {
#pragma unroll
      for (int r = 0; r < 4; ++r) xl[r0 + r][t * 16 + (l & 15)] = acc[i][r];
    }
  }
  __syncthreads();
  for (int bb = w; bb < 16; bb += 4) {
    const int b = m0 + bb;
    float v[5];
    float sum = 0.f, sq = 0.f;
#pragma unroll
    for (int k = 0; k < 5; ++k) {
      const int o = l + 64 * k;
      v[k] = 0.f;
      if (o < 272) {
        const float r = (o < 172) ? node[(size_t)b * 172 + o] : timef[(size_t)b * 100 + (o - 172)];
        const float x = xl[bb][o] + bO[o] + r;
        v[k] = x;
        sum += x;
        sq = fmaf(x, x, sq);
      }
    }
#pragma unroll
    for (int off = 32; off >= 1; off >>= 1) {
      sum += __shfl_xor(sum, off, 64);
      sq += __shfl_xor(sq, off, 64);
    }
    const float mu = sum * (1.0f / 272.0f);
    const float var = sq * (1.0f / 272.0f) - mu * mu;
    const float rs = rsqrtf(var + kLnEps);
#pragma unroll
    for (int k = 0; k < 5; ++k) {
      const int o = l + 64 * k;
      if (o < 272) out[(size_t)b * 272 + o] = (v[k] - mu) * rs * g[o] + be[o];
    }
  }
}

extern "C" void kernel_launch(void* const* d_in, const int* in_sizes, int n_in,
                              void* d_out, int out_size, void* d_ws, size_t ws_size,
                              hipStream_t stream) {
  const float* node = (const float*)d_in[0];
  const float* timef = (const float*)d_in[1];
  const float* nnode = (const float*)d_in[2];
  const float* ntime = (const float*)d_in[3];
  const float* nedge = (const float*)d_in[4];
  const int* mask = (const int*)d_in[5];
  const float* WQ = (const float*)d_in[6];
  const float* WK = (const float*)d_in[7];
  const float* WV = (const float*)d_in[8];
  const float* WO = (const float*)d_in[9];
  const float* bO = (const float*)d_in[10];
  const float* g = (const float*)d_in[11];
  const float* be = (const float*)d_in[12];

  char* ws = (char*)d_ws;
  float* WOT = (float*)(ws + kOffWOT);
  unsigned short* Msw = (unsigned short*)(ws + kOffMsw);
  unsigned short* Psw = (unsigned short*)(ws + kOffPsw);
  unsigned short* A16 = (unsigned short*)(ws + kOffA16);
  unsigned short* QT16 = (unsigned short*)(ws + kOffQT16);
  float* out = (float*)d_out;

  hipLaunchKernelGGL(k_transpose_wo, dim3((272 * 272 + 255) / 256), dim3(256), 0, stream, WO, WOT);
  hipLaunchKernelGGL(k_build_msw, dim3(56 * 9), dim3(64), 0, stream, WQ, WK, Msw);
  hipLaunchKernelGGL(k_build_psw, dim3(17 * 28), dim3(64), 0, stream, WOT, WV, Psw);
  hipLaunchKernelGGL(k_cast_q, dim3(16384 * 288 / 256), dim3(256), 0, stream, node, timef, A16);
  hipLaunchKernelGGL(k_gemm_a, dim3(kB / 16), dim3(256), 0, stream, A16, Msw, QT16);
  hipLaunchKernelGGL(k_attn, dim3(kB / 4), dim3(256), 0, stream, nnode, nedge, ntime, mask, QT16);
  hipLaunchKernelGGL(k_out_mfma, dim3(kB / 16), dim3(256), 0, stream, QT16, Psw, node, timef, bO, g, be, out);
}

// Round 3
// 327.390 us; speedup vs baseline: 2.3260x; 1.0196x over previous
//
#include <hip/hip_runtime.h>

// TemporalAttention, algebraically folded + MFMA for the two matvec phases.
//   A-phase: QT[B,896] = q[B,288(pad)] @ Mmat[288,896]   (bf16 MFMA, cast fused)
//   B-phase: online-softmax attention over kv (fp32, streaming, 4-wide + prefetch)
//   C-phase: X[B,272] = VT[B,896] @ Pmat[896,272] + bias + residual + LN
// Column layout jj' = h*448 + j (j<444 valid, 444..447 pad, per head h).

namespace {
constexpr int kB = 16384;
constexpr int kN = 20;
constexpr float kScale = 0.08574929257125441f;  // 1/sqrt(136)
constexpr float kLnEps = 1e-5f;

// ws byte offsets
constexpr size_t kOffWOT = 0;                         // float[272*272]
constexpr size_t kOffMsw = 295936;                    // ushort[56*9*64*8]
constexpr size_t kOffPsw = kOffMsw + 516096;          // ushort[17*28*64*8]
constexpr size_t kOffQT16 = kOffPsw + 487424;         // ushort[16384*896]
}  // namespace

typedef __attribute__((ext_vector_type(8))) short s8v;
typedef __attribute__((ext_vector_type(4))) float f4v;

__device__ __forceinline__ unsigned short f2bf(float x) {
  unsigned int u = __float_as_uint(x);
  unsigned int r = (u + 0x7FFFu + ((u >> 16) & 1u)) >> 16;
  return (unsigned short)r;
}
__device__ __forceinline__ float bf2f(unsigned short h) {
  return __uint_as_float(((unsigned int)h) << 16);
}
__device__ __forceinline__ float fma4(float4 a, float4 b, float acc) {
  acc = fmaf(a.x, b.x, acc);
  acc = fmaf(a.y, b.y, acc);
  acc = fmaf(a.z, b.z, acc);
  acc = fmaf(a.w, b.w, acc);
  return acc;
}

__global__ __launch_bounds__(256) void k_transpose_wo(const float* __restrict__ WO,
                                                      float* __restrict__ WOT) {
  int idx = blockIdx.x * 256 + threadIdx.x;
  if (idx >= 272 * 272) return;
  int i = idx / 272, o = idx % 272;
  WOT[idx] = WO[o * 272 + i];  // WOT[i][o]
}

// Msw[tile 0..55][ks 0..8][lane][e 0..7]: B-frag order for GEMM-A.
__global__ __launch_bounds__(64) void k_build_msw(const float* __restrict__ WQ,
                                                  const float* __restrict__ WK,
                                                  unsigned short* __restrict__ Msw) {
  const int tile = blockIdx.x / 9;
  const int ks = blockIdx.x % 9;
  const int l = threadIdx.x;
  const int jj = tile * 16 + (l & 15);
  const int h = jj / 448;
  const int j = jj - h * 448;
  const int i0 = ks * 32 + (l >> 4) * 8;
  const bool jvalid = (j < 444);
  unsigned short* dst = Msw + ((size_t)(tile * 9 + ks) * 64 + l) * 8;
#pragma unroll
  for (int e = 0; e < 8; ++e) {
    const int i = i0 + e;
    float s = 0.f;
    if (jvalid && i < 272) {
      const float* wq = WQ + h * 136 * 272 + i;
      const float* wk = WK + h * 136 * 444 + j;
#pragma unroll 4
      for (int d = 0; d < 136; ++d) s = fmaf(wq[d * 272], wk[d * 444], s);
    }
    dst[e] = f2bf(s);
  }
}

// Psw[tile 0..16][ks 0..27][lane][e]: B-frag order for GEMM-C.
__global__ __launch_bounds__(64) void k_build_psw(const float* __restrict__ WOT,
                                                  const float* __restrict__ WV,
                                                  unsigned short* __restrict__ Psw) {
  const int tile = blockIdx.x / 28;
  const int ks = blockIdx.x % 28;
  const int l = threadIdx.x;
  const int n = tile * 16 + (l & 15);
  const int k0 = ks * 32 + (l >> 4) * 8;
  unsigned short* dst = Psw + ((size_t)(tile * 28 + ks) * 64 + l) * 8;
#pragma unroll
  for (int e = 0; e < 8; ++e) {
    const int k = k0 + e;
    const int h = k / 448;
    const int j = k - h * 448;
    float s = 0.f;
    if (j < 444) {
      const float* wo = WOT + h * 136 * 272 + n;
      const float* wv = WV + h * 136 * 444 + j;
#pragma unroll 4
      for (int d = 0; d < 136; ++d) s = fmaf(wo[d * 272], wv[d * 444], s);
    }
    dst[e] = f2bf(s);
  }
}

// GEMM-A (cast fused): QT16[16 rows/block][896] = bf16(q) @ Mmat.
__global__ __launch_bounds__(256) void k_gemm_a(const float* __restrict__ node,
                                                const float* __restrict__ timef,
                                                const unsigned short* __restrict__ Msw,
                                                unsigned short* __restrict__ QT16) {
  const int tid = threadIdx.x;
  const int l = tid & 63, w = tid >> 6;
  const int m0 = blockIdx.x * 16;
  const int mrow = m0 + (l & 15);
  const int koff = (l >> 4) * 8;
  const float4* n4 = reinterpret_cast<const float4*>(node + (size_t)mrow * 172);
  const float4* t4 = reinterpret_cast<const float4*>(timef + (size_t)mrow * 100);
  const float4 z4 = make_float4(0.f, 0.f, 0.f, 0.f);
  f4v acc[14];
#pragma unroll
  for (int t = 0; t < 14; ++t) acc[t] = (f4v){0.f, 0.f, 0.f, 0.f};
  for (int ks = 0; ks < 9; ++ks) {
    const int c0 = ks * 32 + koff;
    float4 lo = z4, hi = z4;
    if (c0 + 8 <= 172) {
      lo = n4[c0 / 4];
      hi = n4[c0 / 4 + 1];
    } else if (c0 == 168) {
      lo = n4[42];
      hi = t4[0];
    } else if (c0 + 8 <= 272) {
      lo = t4[(c0 - 172) / 4];
      hi = t4[(c0 - 172) / 4 + 1];
    }
    s8v a;
    a[0] = (short)f2bf(lo.x); a[1] = (short)f2bf(lo.y);
    a[2] = (short)f2bf(lo.z); a[3] = (short)f2bf(lo.w);
    a[4] = (short)f2bf(hi.x); a[5] = (short)f2bf(hi.y);
    a[6] = (short)f2bf(hi.z); a[7] = (short)f2bf(hi.w);
    const unsigned short* bp = Msw + ((size_t)(w * 14) * 9 + ks) * 64 * 8 + (size_t)l * 8;
#pragma unroll
    for (int t = 0; t < 14; ++t) {
      const s8v b = *reinterpret_cast<const s8v*>(bp + (size_t)t * 9 * 64 * 8);
      acc[t] = __builtin_amdgcn_mfma_f32_16x16x32_bf16(a, b, acc[t], 0, 0, 0);
    }
  }
  const int r0 = (l >> 4) * 4;
#pragma unroll
  for (int t = 0; t < 14; ++t) {
    const int n = (w * 14 + t) * 16 + (l & 15);
#pragma unroll
    for (int r = 0; r < 4; ++r)
      QT16[(size_t)(m0 + r0 + r) * 896 + n] = f2bf(acc[t][r]);
  }
}

// Phase B: one wave per batch row; 4 neighbors/iter; online softmax; prefetch.
__global__ __launch_bounds__(256) void k_attn(const float* __restrict__ nnode,
                                              const float* __restrict__ nedge,
                                              const float* __restrict__ ntime,
                                              const int* __restrict__ mask,
                                              unsigned short* __restrict__ QT16) {
  const int l = threadIdx.x & 63;
  const int w = threadIdx.x >> 6;
  const int b = blockIdx.x * 4 + w;
  const bool v1 = (l < 47);
  const float4* nnode4 = reinterpret_cast<const float4*>(nnode);  // rows of 43
  const float4* nedge4 = reinterpret_cast<const float4*>(nedge);  // rows of 43
  const float4* ntime4 = reinterpret_cast<const float4*>(ntime);  // rows of 25
  const float4 z4 = make_float4(0.f, 0.f, 0.f, 0.f);
  unsigned short* qrow = QT16 + (size_t)b * 896;

  auto ldq = [&](int so) {
    const ushort4 u = *reinterpret_cast<const ushort4*>(qrow + so);
    return make_float4(bf2f(u.x), bf2f(u.y), bf2f(u.z), bf2f(u.w));
  };
  const float4 q00 = ldq(4 * l);
  const float4 q01 = v1 ? ldq(256 + 4 * l) : z4;
  const float4 q10 = ldq(448 + 4 * l);
  const float4 q11 = v1 ? ldq(448 + 256 + 4 * l) : z4;

  auto ldkv = [&](int n, float4& k0, float4& k1) {
    const size_t row = (size_t)b * kN + n;
    k0 = (l < 43) ? nnode4[row * 43 + l] : nedge4[row * 43 + (l - 43)];
    k1 = z4;
    if (v1) {
      const int j4 = 64 + l;
      k1 = (j4 < 86) ? nedge4[row * 43 + (j4 - 43)] : ntime4[row * 25 + (j4 - 86)];
    }
  };

  float4 c[4][2], pf[4][2];
#pragma unroll
  for (int a = 0; a < 4; ++a) ldkv(a, c[a][0], c[a][1]);
  const int4* mrow4 = reinterpret_cast<const int4*>(mask + (size_t)b * kN);

  float4 va00 = z4, va01 = z4, va10 = z4, va11 = z4;
  float m0 = -1e30f, m1 = -1e30f, l0 = 0.f, l1 = 0.f;

  for (int it = 0; it < 5; ++it) {
    if (it < 4) {
#pragma unroll
      for (int a = 0; a < 4; ++a) ldkv(4 * (it + 1) + a, pf[a][0], pf[a][1]);
    }
    const int4 mk = mrow4[it];
    float ps[4][2];
#pragma unroll
    for (int a = 0; a < 4; ++a) {
      ps[a][0] = fma4(q01, c[a][1], fma4(q00, c[a][0], 0.f));
      ps[a][1] = fma4(q11, c[a][1], fma4(q10, c[a][0], 0.f));
    }
#pragma unroll
    for (int off = 32; off >= 1; off >>= 1) {
#pragma unroll
      for (int a = 0; a < 4; ++a) {
        ps[a][0] += __shfl_xor(ps[a][0], off, 64);
        ps[a][1] += __shfl_xor(ps[a][1], off, 64);
      }
    }
    float s[4][2];
    s[0][0] = (mk.x == 0) ? -1e10f : ps[0][0] * kScale;
    s[0][1] = (mk.x == 0) ? -1e10f : ps[0][1] * kScale;
    s[1][0] = (mk.y == 0) ? -1e10f : ps[1][0] * kScale;
    s[1][1] = (mk.y == 0) ? -1e10f : ps[1][1] * kScale;
    s[2][0] = (mk.z == 0) ? -1e10f : ps[2][0] * kScale;
    s[2][1] = (mk.z == 0) ? -1e10f : ps[2][1] * kScale;
    s[3][0] = (mk.w == 0) ? -1e10f : ps[3][0] * kScale;
    s[3][1] = (mk.w == 0) ? -1e10f : ps[3][1] * kScale;
    // head 0
    {
      const float mn = fmaxf(m0, fmaxf(fmaxf(s[0][0], s[1][0]), fmaxf(s[2][0], s[3][0])));
      const float al = __expf(m0 - mn);
      const float p0 = __expf(s[0][0] - mn);
      const float p1 = __expf(s[1][0] - mn);
      const float p2 = __expf(s[2][0] - mn);
      const float p3 = __expf(s[3][0] - mn);
      m0 = mn;
      l0 = fmaf(l0, al, p0 + p1 + p2 + p3);
      va00.x = fmaf(p3, c[3][0].x, fmaf(p2, c[2][0].x, fmaf(p1, c[1][0].x, fmaf(p0, c[0][0].x, va00.x * al))));
      va00.y = fmaf(p3, c[3][0].y, fmaf(p2, c[2][0].y, fmaf(p1, c[1][0].y, fmaf(p0, c[0][0].y, va00.y * al))));
      va00.z = fmaf(p3, c[3][0].z, fmaf(p2, c[2][0].z, fmaf(p1, c[1][0].z, fmaf(p0, c[0][0].z, va00.z * al))));
      va00.w = fmaf(p3, c[3][0].w, fmaf(p2, c[2][0].w, fmaf(p1, c[1][0].w, fmaf(p0, c[0][0].w, va00.w * al))));
      va01.x = fmaf(p3, c[3][1].x, fmaf(p2, c[2][1].x, fmaf(p1, c[1][1].x, fmaf(p0, c[0][1].x, va01.x * al))));
      va01.y = fmaf(p3, c[3][1].y, fmaf(p2, c[2][1].y, fmaf(p1, c[1][1].y, fmaf(p0, c[0][1].y, va01.y * al))));
      va01.z = fmaf(p3, c[3][1].z, fmaf(p2, c[2][1].z, fmaf(p1, c[1][1].z, fmaf(p0, c[0][1].z, va01.z * al))));
      va01.w = fmaf(p3, c[3][1].w, fmaf(p2, c[2][1].w, fmaf(p1, c[1][1].w, fmaf(p0, c[0][1].w, va01.w * al))));
    }
    // head 1
    {
      const float mn = fmaxf(m1, fmaxf(fmaxf(s[0][1], s[1][1]), fmaxf(s[2][1], s[3][1])));
      const float al = __expf(m1 - mn);
      const float p0 = __expf(s[0][1] - mn);
      const float p1 = __expf(s[1][1] - mn);
      const float p2 = __expf(s[2][1] - mn);
      const float p3 = __expf(s[3][1] - mn);
      m1 = mn;
      l1 = fmaf(l1, al, p0 + p1 + p2 + p3);
      va10.x = fmaf(p3, c[3][0].x, fmaf(p2, c[2][0].x, fmaf(p1, c[1][0].x, fmaf(p0, c[0][0].x, va10.x * al))));
      va10.y = fmaf(p3, c[3][0].y, fmaf(p2, c[2][0].y, fmaf(p1, c[1][0].y, fmaf(p0, c[0][0].y, va10.y * al))));
      va10.z = fmaf(p3, c[3][0].z, fmaf(p2, c[2][0].z, fmaf(p1, c[1][0].z, fmaf(p0, c[0][0].z, va10.z * al))));
      va10.w = fmaf(p3, c[3][0].w, fmaf(p2, c[2][0].w, fmaf(p1, c[1][0].w, fmaf(p0, c[0][0].w, va10.w * al))));
      va11.x = fmaf(p3, c[3][1].x, fmaf(p2, c[2][1].x, fmaf(p1, c[1][1].x, fmaf(p0, c[0][1].x, va11.x * al))));
      va11.y = fmaf(p3, c[3][1].y, fmaf(p2, c[2][1].y, fmaf(p1, c[1][1].y, fmaf(p0, c[0][1].y, va11.y * al))));
      va11.z = fmaf(p3, c[3][1].z, fmaf(p2, c[2][1].z, fmaf(p1, c[1][1].z, fmaf(p0, c[0][1].z, va11.z * al))));
      va11.w = fmaf(p3, c[3][1].w, fmaf(p2, c[2][1].w, fmaf(p1, c[1][1].w, fmaf(p0, c[0][1].w, va11.w * al))));
    }
    if (it < 4) {
#pragma unroll
      for (int a = 0; a < 4; ++a) {
        c[a][0] = pf[a][0];
        c[a][1] = pf[a][1];
      }
    }
  }
  const float i0 = 1.0f / l0;
  const float i1 = 1.0f / l1;
  auto stq = [&](int so, float4 v, float s) {
    ushort4 u;
    u.x = f2bf(v.x * s); u.y = f2bf(v.y * s); u.z = f2bf(v.z * s); u.w = f2bf(v.w * s);
    *reinterpret_cast<ushort4*>(qrow + so) = u;
  };
  stq(4 * l, va00, i0);
  if (v1) stq(256 + 4 * l, va01, i0);
  stq(448 + 4 * l, va10, i1);
  if (v1) stq(448 + 256 + 4 * l, va11, i1);
}

// GEMM-C + bias + residual + LayerNorm. 4 waves; wave w owns n-tiles w,w+4,...
__global__ __launch_bounds__(256) void k_out_mfma(const unsigned short* __restrict__ VT16,
                                                  const unsigned short* __restrict__ Psw,
                                                  const float* __restrict__ node,
                                                  const float* __restrict__ timef,
                                                  const float* __restrict__ bO,
                                                  const float* __restrict__ g,
                                                  const float* __restrict__ be,
                                                  float* __restrict__ out) {
  __shared__ float xl[16][273];
  const int tid = threadIdx.x;
  const int l = tid & 63, w = tid >> 6;
  const int m0 = blockIdx.x * 16;
  const int mrow = m0 + (l & 15);
  const int koff = (l >> 4) * 8;
  f4v acc[5];
#pragma unroll
  for (int i = 0; i < 5; ++i) acc[i] = (f4v){0.f, 0.f, 0.f, 0.f};
  for (int ks = 0; ks < 28; ++ks) {
    const s8v a = *reinterpret_cast<const s8v*>(VT16 + (size_t)mrow * 896 + ks * 32 + koff);
#pragma unroll
    for (int i = 0; i < 5; ++i) {
      const int t = w + 4 * i;
      if (t < 17) {
        const s8v bfr = *reinterpret_cast<const s8v*>(Psw + ((size_t)(t * 28 + ks) * 64 + l) * 8);
        acc[i] = __builtin_amdgcn_mfma_f32_16x16x32_bf16(a, bfr, acc[i], 0, 0, 0);
      }
    }
  }
  const int r0 = (l >> 4) * 4;
#pragma unroll
  for (int i = 0; i < 5; ++i) {
    const int t = w + 4 * i;
    if (t < 17) {
#pragma unroll
      for (int r = 0; r < 4; ++r) xl[r0 + r][t * 16 + (l & 15)] = acc[i][r];
    }
  }
  __syncthreads();
  for (int bb = w; bb < 16; bb += 4) {
    const int b = m0 + bb;
    float v[5];
    float sum = 0.f, sq = 0.f;
#pragma unroll
    for (int k = 0; k < 5; ++k) {
      const int o = l + 64 * k;
      v[k] = 0.f;
      if (o < 272) {
        const float r = (o < 172) ? node[(size_t)b * 172 + o] : timef[(size_t)b * 100 + (o - 172)];
        const float x = xl[bb][o] + bO[o] + r;
        v[k] = x;
        sum += x;
        sq = fmaf(x, x, sq);
      }
    }
#pragma unroll
    for (int off = 32; off >= 1; off >>= 1) {
      sum += __shfl_xor(sum, off, 64);
      sq += __shfl_xor(sq, off, 64);
    }
    const float mu = sum * (1.0f / 272.0f);
    const float var = sq * (1.0f / 272.0f) - mu * mu;
    const float rs = rsqrtf(var + kLnEps);
#pragma unroll
    for (int k = 0; k < 5; ++k) {
      const int o = l + 64 * k;
      if (o < 272) out[(size_t)b * 272 + o] = (v[k] - mu) * rs * g[o] + be[o];
    }
  }
}

extern "C" void kernel_launch(void* const* d_in, const int* in_sizes, int n_in,
                              void* d_out, int out_size, void* d_ws, size_t ws_size,
                              hipStream_t stream) {
  const float* node = (const float*)d_in[0];
  const float* timef = (const float*)d_in[1];
  const float* nnode = (const float*)d_in[2];
  const float* ntime = (const float*)d_in[3];
  const float* nedge = (const float*)d_in[4];
  const int* mask = (const int*)d_in[5];
  const float* WQ = (const float*)d_in[6];
  const float* WK = (const float*)d_in[7];
  const float* WV = (const float*)d_in[8];
  const float* WO = (const float*)d_in[9];
  const float* bO = (const float*)d_in[10];
  const float* g = (const float*)d_in[11];
  const float* be = (const float*)d_in[12];

  char* ws = (char*)d_ws;
  float* WOT = (float*)(ws + kOffWOT);
  unsigned short* Msw = (unsigned short*)(ws + kOffMsw);
  unsigned short* Psw = (unsigned short*)(ws + kOffPsw);
  unsigned short* QT16 = (unsigned short*)(ws + kOffQT16);
  float* out = (float*)d_out;

  hipLaunchKernelGGL(k_transpose_wo, dim3((272 * 272 + 255) / 256), dim3(256), 0, stream, WO, WOT);
  hipLaunchKernelGGL(k_build_msw, dim3(56 * 9), dim3(64), 0, stream, WQ, WK, Msw);
  hipLaunchKernelGGL(k_build_psw, dim3(17 * 28), dim3(64), 0, stream, WOT, WV, Psw);
  hipLaunchKernelGGL(k_gemm_a, dim3(kB / 16), dim3(256), 0, stream, node, timef, Msw, QT16);
  hipLaunchKernelGGL(k_attn, dim3(kB / 4), dim3(256), 0, stream, nnode, nedge, ntime, mask, QT16);
  hipLaunchKernelGGL(k_out_mfma, dim3(kB / 16), dim3(256), 0, stream, QT16, Psw, node, timef, bO, g, be, out);
}

// Round 4
// 264.063 us; speedup vs baseline: 2.8838x; 1.2398x over previous
//
#include <hip/hip_runtime.h>

// TemporalAttention, algebraically folded + MFMA for the two matvec phases.
//   A-phase: QT[B,896] = q[B,288(pad)] @ Mmat[288,896]   (bf16 MFMA, cast fused)
//   B-phase: online-softmax attention, 4 neighbor-groups x 16 lanes per wave
//   C-phase: X[B,272] = VT[B,896] @ Pmat[896,272] + bias + residual + LN
// Column layout jj' = h*448 + j (j<444 valid, 444..447 pad, per head h).

namespace {
constexpr int kB = 16384;
constexpr int kN = 20;
constexpr float kScale = 0.08574929257125441f;  // 1/sqrt(136)
constexpr float kLnEps = 1e-5f;

// ws byte offsets
constexpr size_t kOffWOT = 0;                         // float[272*272]
constexpr size_t kOffMsw = 295936;                    // ushort[56*9*64*8]
constexpr size_t kOffPsw = kOffMsw + 516096;          // ushort[17*28*64*8]
constexpr size_t kOffQT16 = kOffPsw + 487424;         // ushort[16384*896]
}  // namespace

typedef __attribute__((ext_vector_type(8))) short s8v;
typedef __attribute__((ext_vector_type(4))) float f4v;

__device__ __forceinline__ unsigned short f2bf(float x) {
  unsigned int u = __float_as_uint(x);
  unsigned int r = (u + 0x7FFFu + ((u >> 16) & 1u)) >> 16;
  return (unsigned short)r;
}
__device__ __forceinline__ float bf2f(unsigned short h) {
  return __uint_as_float(((unsigned int)h) << 16);
}
__device__ __forceinline__ float fma4(float4 a, float4 b, float acc) {
  acc = fmaf(a.x, b.x, acc);
  acc = fmaf(a.y, b.y, acc);
  acc = fmaf(a.z, b.z, acc);
  acc = fmaf(a.w, b.w, acc);
  return acc;
}

__global__ __launch_bounds__(256) void k_transpose_wo(const float* __restrict__ WO,
                                                      float* __restrict__ WOT) {
  int idx = blockIdx.x * 256 + threadIdx.x;
  if (idx >= 272 * 272) return;
  int i = idx / 272, o = idx % 272;
  WOT[idx] = WO[o * 272 + i];  // WOT[i][o]
}

// Msw[tile 0..55][ks 0..8][lane][e 0..7]: B-frag order for GEMM-A.
// Block = (tile, ks, e); lane computes one element's 136-dot.
__global__ __launch_bounds__(64) void k_build_msw(const float* __restrict__ WQ,
                                                  const float* __restrict__ WK,
                                                  unsigned short* __restrict__ Msw) {
  const int e = blockIdx.x % 8;
  const int ks = (blockIdx.x / 8) % 9;
  const int tile = blockIdx.x / 72;
  const int l = threadIdx.x;
  const int jj = tile * 16 + (l & 15);
  const int h = jj / 448;
  const int j = jj - h * 448;
  const int i = ks * 32 + (l >> 4) * 8 + e;
  float s = 0.f;
  if (j < 444 && i < 272) {
    const float* wq = WQ + h * 136 * 272 + i;
    const float* wk = WK + h * 136 * 444 + j;
#pragma unroll 8
    for (int d = 0; d < 136; ++d) s = fmaf(wq[d * 272], wk[d * 444], s);
  }
  Msw[((size_t)(tile * 9 + ks) * 64 + l) * 8 + e] = f2bf(s);
}

// Psw[tile 0..16][ks 0..27][lane][e]: B-frag order for GEMM-C.
__global__ __launch_bounds__(64) void k_build_psw(const float* __restrict__ WOT,
                                                  const float* __restrict__ WV,
                                                  unsigned short* __restrict__ Psw) {
  const int e = blockIdx.x % 8;
  const int ks = (blockIdx.x / 8) % 28;
  const int tile = blockIdx.x / 224;
  const int l = threadIdx.x;
  const int n = tile * 16 + (l & 15);
  const int k = ks * 32 + (l >> 4) * 8 + e;
  const int h = k / 448;
  const int j = k - h * 448;
  float s = 0.f;
  if (j < 444) {
    const float* wo = WOT + h * 136 * 272 + n;
    const float* wv = WV + h * 136 * 444 + j;
#pragma unroll 8
    for (int d = 0; d < 136; ++d) s = fmaf(wo[d * 272], wv[d * 444], s);
  }
  Psw[((size_t)(tile * 28 + ks) * 64 + l) * 8 + e] = f2bf(s);
}

// GEMM-A (cast fused): QT16[16 rows/block][896] = bf16(q) @ Mmat.
__global__ __launch_bounds__(256) void k_gemm_a(const float* __restrict__ node,
                                                const float* __restrict__ timef,
                                                const unsigned short* __restrict__ Msw,
                                                unsigned short* __restrict__ QT16) {
  const int tid = threadIdx.x;
  const int l = tid & 63, w = tid >> 6;
  const int m0 = blockIdx.x * 16;
  const int mrow = m0 + (l & 15);
  const int koff = (l >> 4) * 8;
  const float4* n4 = reinterpret_cast<const float4*>(node + (size_t)mrow * 172);
  const float4* t4 = reinterpret_cast<const float4*>(timef + (size_t)mrow * 100);
  const float4 z4 = make_float4(0.f, 0.f, 0.f, 0.f);
  f4v acc[14];
#pragma unroll
  for (int t = 0; t < 14; ++t) acc[t] = (f4v){0.f, 0.f, 0.f, 0.f};
  for (int ks = 0; ks < 9; ++ks) {
    const int c0 = ks * 32 + koff;
    float4 lo = z4, hi = z4;
    if (c0 + 8 <= 172) {
      lo = n4[c0 / 4];
      hi = n4[c0 / 4 + 1];
    } else if (c0 == 168) {
      lo = n4[42];
      hi = t4[0];
    } else if (c0 + 8 <= 272) {
      lo = t4[(c0 - 172) / 4];
      hi = t4[(c0 - 172) / 4 + 1];
    }
    s8v a;
    a[0] = (short)f2bf(lo.x); a[1] = (short)f2bf(lo.y);
    a[2] = (short)f2bf(lo.z); a[3] = (short)f2bf(lo.w);
    a[4] = (short)f2bf(hi.x); a[5] = (short)f2bf(hi.y);
    a[6] = (short)f2bf(hi.z); a[7] = (short)f2bf(hi.w);
    const unsigned short* bp = Msw + ((size_t)(w * 14) * 9 + ks) * 64 * 8 + (size_t)l * 8;
#pragma unroll
    for (int t = 0; t < 14; ++t) {
      const s8v b = *reinterpret_cast<const s8v*>(bp + (size_t)t * 9 * 64 * 8);
      acc[t] = __builtin_amdgcn_mfma_f32_16x16x32_bf16(a, b, acc[t], 0, 0, 0);
    }
  }
  const int r0 = (l >> 4) * 4;
#pragma unroll
  for (int t = 0; t < 14; ++t) {
    const int n = (w * 14 + t) * 16 + (l & 15);
#pragma unroll
    for (int r = 0; r < 4; ++r)
      QT16[(size_t)(m0 + r0 + r) * 896 + n] = f2bf(acc[t][r]);
  }
}

// Phase B: one wave per row; lanes = 4 neighbor-groups (g) x 16 slices (p).
// Group g handles neighbor n = 4*it + g with its own online-softmax state;
// slice: j4 = p + 16k, k=0..6 (interleaved -> 256B coalesced per group).
// States merged across groups once at the end (2 shfl steps).
__global__ __launch_bounds__(256) void k_attn(const float* __restrict__ nnode,
                                              const float* __restrict__ nedge,
                                              const float* __restrict__ ntime,
                                              const int* __restrict__ mask,
                                              unsigned short* __restrict__ QT16) {
  const int lane = threadIdx.x & 63;
  const int wv = threadIdx.x >> 6;
  const int b = blockIdx.x * 4 + wv;
  const int g = lane >> 4;
  const int p = lane & 15;
  const float4* nnode4 = reinterpret_cast<const float4*>(nnode);  // rows of 43
  const float4* nedge4 = reinterpret_cast<const float4*>(nedge);  // rows of 43
  const float4* ntime4 = reinterpret_cast<const float4*>(ntime);  // rows of 25
  const float4 z4 = make_float4(0.f, 0.f, 0.f, 0.f);
  unsigned short* qrow = QT16 + (size_t)b * 896;

  // unpack q~ slices (pad region 444..447 is zero, safe)
  float4 qf[2][7];
#pragma unroll
  for (int h = 0; h < 2; ++h)
#pragma unroll
    for (int k = 0; k < 7; ++k) {
      const int j4 = p + 16 * k;
      const ushort4 u = *reinterpret_cast<const ushort4*>(qrow + h * 448 + 4 * j4);
      qf[h][k] = make_float4(bf2f(u.x), bf2f(u.y), bf2f(u.z), bf2f(u.w));
    }
  int mk[5];
#pragma unroll
  for (int it = 0; it < 5; ++it) mk[it] = mask[(size_t)b * kN + it * 4 + g];

  auto ldkv = [&](int n, float4* dst) {
    const size_t row = (size_t)b * kN + n;
#pragma unroll
    for (int k = 0; k < 7; ++k) {
      const int j4 = p + 16 * k;
      float4 v;
      if (k <= 1) {
        v = nnode4[row * 43 + j4];
      } else if (k == 2) {
        v = (j4 < 43) ? nnode4[row * 43 + j4] : nedge4[row * 43 + (j4 - 43)];
      } else if (k <= 4) {
        v = nedge4[row * 43 + (j4 - 43)];
      } else if (k == 5) {
        v = (j4 < 86) ? nedge4[row * 43 + (j4 - 43)] : ntime4[row * 25 + (j4 - 86)];
      } else {
        v = (j4 < 111) ? ntime4[row * 25 + (j4 - 86)] : z4;
      }
      dst[k] = v;
    }
  };

  float4 cur[7], pf[7];
  ldkv(g, cur);
  float4 va0[7], va1[7];
#pragma unroll
  for (int k = 0; k < 7; ++k) { va0[k] = z4; va1[k] = z4; }
  float m0 = -1e30f, m1 = -1e30f, l0 = 0.f, l1 = 0.f;

#pragma unroll
  for (int it = 0; it < 5; ++it) {
    if (it < 4) ldkv(4 * (it + 1) + g, pf);
    float ps0 = 0.f, ps1 = 0.f;
#pragma unroll
    for (int k = 0; k < 7; ++k) {
      ps0 = fma4(qf[0][k], cur[k], ps0);
      ps1 = fma4(qf[1][k], cur[k], ps1);
    }
#pragma unroll
    for (int off = 8; off >= 1; off >>= 1) {
      ps0 += __shfl_xor(ps0, off, 64);
      ps1 += __shfl_xor(ps1, off, 64);
    }
    const bool msk = (mk[it] == 0);
    const float sc0 = msk ? -1e10f : ps0 * kScale;
    const float sc1 = msk ? -1e10f : ps1 * kScale;
    const float mn0 = fmaxf(m0, sc0);
    const float al0 = __expf(m0 - mn0);
    const float pp0 = __expf(sc0 - mn0);
    m0 = mn0;
    l0 = fmaf(l0, al0, pp0);
    const float mn1 = fmaxf(m1, sc1);
    const float al1 = __expf(m1 - mn1);
    const float pp1 = __expf(sc1 - mn1);
    m1 = mn1;
    l1 = fmaf(l1, al1, pp1);
#pragma unroll
    for (int k = 0; k < 7; ++k) {
      va0[k].x = fmaf(pp0, cur[k].x, va0[k].x * al0);
      va0[k].y = fmaf(pp0, cur[k].y, va0[k].y * al0);
      va0[k].z = fmaf(pp0, cur[k].z, va0[k].z * al0);
      va0[k].w = fmaf(pp0, cur[k].w, va0[k].w * al0);
      va1[k].x = fmaf(pp1, cur[k].x, va1[k].x * al1);
      va1[k].y = fmaf(pp1, cur[k].y, va1[k].y * al1);
      va1[k].z = fmaf(pp1, cur[k].z, va1[k].z * al1);
      va1[k].w = fmaf(pp1, cur[k].w, va1[k].w * al1);
    }
    if (it < 4) {
#pragma unroll
      for (int k = 0; k < 7; ++k) cur[k] = pf[k];
    }
  }

  // merge the 4 group states (lanes same p, different g)
  float M0 = m0, M1 = m1;
  M0 = fmaxf(M0, __shfl_xor(M0, 16, 64));
  M0 = fmaxf(M0, __shfl_xor(M0, 32, 64));
  M1 = fmaxf(M1, __shfl_xor(M1, 16, 64));
  M1 = fmaxf(M1, __shfl_xor(M1, 32, 64));
  const float f0 = __expf(m0 - M0);
  const float f1 = __expf(m1 - M1);
  float L0 = l0 * f0, L1 = l1 * f1;
  L0 += __shfl_xor(L0, 16, 64);
  L0 += __shfl_xor(L0, 32, 64);
  L1 += __shfl_xor(L1, 16, 64);
  L1 += __shfl_xor(L1, 32, 64);
  auto xr = [&](float v) {
    v += __shfl_xor(v, 16, 64);
    v += __shfl_xor(v, 32, 64);
    return v;
  };
#pragma unroll
  for (int k = 0; k < 7; ++k) {
    va0[k].x = xr(va0[k].x * f0);
    va0[k].y = xr(va0[k].y * f0);
    va0[k].z = xr(va0[k].z * f0);
    va0[k].w = xr(va0[k].w * f0);
    va1[k].x = xr(va1[k].x * f1);
    va1[k].y = xr(va1[k].y * f1);
    va1[k].z = xr(va1[k].z * f1);
    va1[k].w = xr(va1[k].w * f1);
  }
  const float i0 = 1.0f / L0;
  const float i1 = 1.0f / L1;
  if (g == 0) {
#pragma unroll
    for (int k = 0; k < 7; ++k) {
      const int j4 = p + 16 * k;
      ushort4 u0, u1;
      u0.x = f2bf(va0[k].x * i0); u0.y = f2bf(va0[k].y * i0);
      u0.z = f2bf(va0[k].z * i0); u0.w = f2bf(va0[k].w * i0);
      u1.x = f2bf(va1[k].x * i1); u1.y = f2bf(va1[k].y * i1);
      u1.z = f2bf(va1[k].z * i1); u1.w = f2bf(va1[k].w * i1);
      *reinterpret_cast<ushort4*>(qrow + 4 * j4) = u0;
      *reinterpret_cast<ushort4*>(qrow + 448 + 4 * j4) = u1;
    }
  }
}

// GEMM-C + bias + residual + LayerNorm. 4 waves; wave w owns n-tiles w,w+4,...
__global__ __launch_bounds__(256) void k_out_mfma(const unsigned short* __restrict__ VT16,
                                                  const unsigned short* __restrict__ Psw,
                                                  const float* __restrict__ node,
                                                  const float* __restrict__ timef,
                                                  const float* __restrict__ bO,
                                                  const float* __restrict__ g,
                                                  const float* __restrict__ be,
                                                  float* __restrict__ out) {
  __shared__ float xl[16][273];
  const int tid = threadIdx.x;
  const int l = tid & 63, w = tid >> 6;
  const int m0 = blockIdx.x * 16;
  const int mrow = m0 + (l & 15);
  const int koff = (l >> 4) * 8;
  f4v acc[5];
#pragma unroll
  for (int i = 0; i < 5; ++i) acc[i] = (f4v){0.f, 0.f, 0.f, 0.f};
  for (int ks = 0; ks < 28; ++ks) {
    const s8v a = *reinterpret_cast<const s8v*>(VT16 + (size_t)mrow * 896 + ks * 32 + koff);
#pragma unroll
    for (int i = 0; i < 5; ++i) {
      const int t = w + 4 * i;
      if (t < 17) {
        const s8v bfr = *reinterpret_cast<const s8v*>(Psw + ((size_t)(t * 28 + ks) * 64 + l) * 8);
        acc[i] = __builtin_amdgcn_mfma_f32_16x16x32_bf16(a, bfr, acc[i], 0, 0, 0);
      }
    }
  }
  const int r0 = (l >> 4) * 4;
#pragma unroll
  for (int i = 0; i < 5; ++i) {
    const int t = w + 4 * i;
    if (t < 17) {
#pragma unroll
      for (int r = 0; r < 4; ++r) xl[r0 + r][t * 16 + (l & 15)] = acc[i][r];
    }
  }
  __syncthreads();
  for (int bb = w; bb < 16; bb += 4) {
    const int b = m0 + bb;
    float v[5];
    float sum = 0.f, sq = 0.f;
#pragma unroll
    for (int k = 0; k < 5; ++k) {
      const int o = l + 64 * k;
      v[k] = 0.f;
      if (o < 272) {
        const float r = (o < 172) ? node[(size_t)b * 172 + o] : timef[(size_t)b * 100 + (o - 172)];
        const float x = xl[bb][o] + bO[o] + r;
        v[k] = x;
        sum += x;
        sq = fmaf(x, x, sq);
      }
    }
#pragma unroll
    for (int off = 32; off >= 1; off >>= 1) {
      sum += __shfl_xor(sum, off, 64);
      sq += __shfl_xor(sq, off, 64);
    }
    const float mu = sum * (1.0f / 272.0f);
    const float var = sq * (1.0f / 272.0f) - mu * mu;
    const float rs = rsqrtf(var + kLnEps);
#pragma unroll
    for (int k = 0; k < 5; ++k) {
      const int o = l + 64 * k;
      if (o < 272) out[(size_t)b * 272 + o] = (v[k] - mu) * rs * g[o] + be[o];
    }
  }
}

extern "C" void kernel_launch(void* const* d_in, const int* in_sizes, int n_in,
                              void* d_out, int out_size, void* d_ws, size_t ws_size,
                              hipStream_t stream) {
  const float* node = (const float*)d_in[0];
  const float* timef = (const float*)d_in[1];
  const float* nnode = (const float*)d_in[2];
  const float* ntime = (const float*)d_in[3];
  const float* nedge = (const float*)d_in[4];
  const int* mask = (const int*)d_in[5];
  const float* WQ = (const float*)d_in[6];
  const float* WK = (const float*)d_in[7];
  const float* WV = (const float*)d_in[8];
  const float* WO = (const float*)d_in[9];
  const float* bO = (const float*)d_in[10];
  const float* g = (const float*)d_in[11];
  const float* be = (const float*)d_in[12];

  char* ws = (char*)d_ws;
  float* WOT = (float*)(ws + kOffWOT);
  unsigned short* Msw = (unsigned short*)(ws + kOffMsw);
  unsigned short* Psw = (unsigned short*)(ws + kOffPsw);
  unsigned short* QT16 = (unsigned short*)(ws + kOffQT16);
  float* out = (float*)d_out;

  hipLaunchKernelGGL(k_transpose_wo, dim3((272 * 272 + 255) / 256), dim3(256), 0, stream, WO, WOT);
  hipLaunchKernelGGL(k_build_msw, dim3(56 * 9 * 8), dim3(64), 0, stream, WQ, WK, Msw);
  hipLaunchKernelGGL(k_build_psw, dim3(17 * 28 * 8), dim3(64), 0, stream, WOT, WV, Psw);
  hipLaunchKernelGGL(k_gemm_a, dim3(kB / 16), dim3(256), 0, stream, node, timef, Msw, QT16);
  hipLaunchKernelGGL(k_attn, dim3(kB / 4), dim3(256), 0, stream, nnode, nedge, ntime, mask, QT16);
  hipLaunchKernelGGL(k_out_mfma, dim3(kB / 16), dim3(256), 0, stream, QT16, Psw, node, timef, bO, g, be, out);
}